// Round 1
// baseline (1134.567 us; speedup 1.0000x reference)
//
#include <hip/hip_runtime.h>
#include <math.h>

// VMD: T = 2^20, K = 3, 50 iterations.
// Workspace layout (needs 32MB + ~8KB):
//   [0,8MB)    f_hat  (float2, s-layout: s = k1*1024+k2, t(s) = ((k2^512)<<10)|k1)
//   [8,16MB)   lam    (float2, s-layout)
//   [16,24MB)  lam_old(float2, s-layout)  -- snapshot of lam at entry of freeze-capable iters
//   [24,32MB)  scratch (float2)           -- FFT intermediate
//   [32MB..)   acc: double[8][64] (slot j at acc[j*64+n], separate cache lines)
//   +4KB       omega0: float[3]

#define ALPHA_F 2000.0f
#define TAU_F   1e-7f

static __device__ __forceinline__ int lpad(int i) { return i + (i >> 5); }
static __device__ __forceinline__ int swz(int i)  { return ((i & 7) << 7) | (i >> 3); }

#define PADN 1057

// ---------------- 1024-point radix-4 Stockham FFT in LDS ----------------
// Natural order in (Ar/Ai), natural order out (Br/Bi). Caller syncs after load.
template<int SIGN>   // -1 = forward (e^{-i}), +1 = inverse (e^{+i}, unscaled)
static __device__ void fft1024(float* Ar, float* Ai, float* Br, float* Bi)
{
  const int u = threadIdx.x;
#pragma unroll
  for (int st = 0; st < 5; ++st) {
    float *ir, *ii, *pr, *pi;
    if (st & 1) { ir = Br; ii = Bi; pr = Ar; pi = Ai; }
    else        { ir = Ar; ii = Ai; pr = Br; pi = Bi; }
    const int quarter = 1 << (2 * st);
    const int p = u & (quarter - 1);
    const int g = u >> (2 * st);

    float sw, cw;
    sincospif((float)(2 * p) * (1.0f / (float)(4 << (2 * st))), &sw, &cw);
    const float w1r = cw,                 w1i = (SIGN < 0) ? -sw : sw;
    const float w2r = w1r*w1r - w1i*w1i,  w2i = 2.0f*w1r*w1i;
    const float w3r = w2r*w1r - w2i*w1i,  w3i = w2r*w1i + w2i*w1r;

    float x0r = ir[lpad(u      )], x0i = ii[lpad(u      )];
    float x1r = ir[lpad(u + 256)], x1i = ii[lpad(u + 256)];
    float x2r = ir[lpad(u + 512)], x2i = ii[lpad(u + 512)];
    float x3r = ir[lpad(u + 768)], x3i = ii[lpad(u + 768)];

    float y1r = x1r*w1r - x1i*w1i, y1i = x1r*w1i + x1i*w1r;
    float y2r = x2r*w2r - x2i*w2i, y2i = x2r*w2i + x2i*w2r;
    float y3r = x3r*w3r - x3i*w3i, y3i = x3r*w3i + x3i*w3r;

    float t0r = x0r + y2r, t0i = x0i + y2i;
    float t1r = x0r - y2r, t1i = x0i - y2i;
    float t2r = y1r + y3r, t2i = y1i + y3i;
    float t3r = y1r - y3r, t3i = y1i - y3i;

    float o0r = t0r + t2r, o0i = t0i + t2i;
    float o2r = t0r - t2r, o2i = t0i - t2i;
    float o1r, o1i, o3r, o3i;
    if (SIGN < 0) { // fwd: out1 = t1 - i*t3 ; out3 = t1 + i*t3
      o1r = t1r + t3i; o1i = t1i - t3r;
      o3r = t1r - t3i; o3i = t1i + t3r;
    } else {        // inv: out1 = t1 + i*t3 ; out3 = t1 - i*t3
      o1r = t1r - t3i; o1i = t1i + t3r;
      o3r = t1r + t3i; o3i = t1i - t3r;
    }
    const int base = (g << (2 * st + 2)) + p;
    pr[lpad(base              )] = o0r; pi[lpad(base              )] = o0i;
    pr[lpad(base +     quarter)] = o1r; pi[lpad(base +     quarter)] = o1i;
    pr[lpad(base + 2 * quarter)] = o2r; pi[lpad(base + 2 * quarter)] = o2i;
    pr[lpad(base + 3 * quarter)] = o3r; pi[lpad(base + 3 * quarter)] = o3i;
    __syncthreads();
  }
}

// ---------------- init ----------------
__global__ __launch_bounds__(256) void k_init(double* acc, float* omega0,
                                              const float* __restrict__ omega_init)
{
  int i = threadIdx.x;
  for (int j = i; j < 8 * 64; j += 256) acc[j] = 0.0;
  if (i < 3) omega0[i] = omega_init[i];
}

// ---------------- forward FFT ----------------
__global__ __launch_bounds__(256) void k_fwd_passA(const float* __restrict__ x,
                                                   float2* __restrict__ ws0)
{
  __shared__ float Ar[PADN], Ai[PADN], Br[PADN], Bi[PADN];
  const int b = swz(blockIdx.x);   // n2
  const int tid = threadIdx.x;
#pragma unroll
  for (int q = 0; q < 4; ++q) {
    int j = tid + 256 * q;         // n1
    Ar[lpad(j)] = x[(size_t)j * 1024 + b];
    Ai[lpad(j)] = 0.0f;
  }
  __syncthreads();
  fft1024<-1>(Ar, Ai, Br, Bi);
#pragma unroll
  for (int q = 0; q < 4; ++q) {
    int k1 = tid + 256 * q;
    int ph = b * k1;               // < 2^20, exact in fp32
    float s, c;
    sincospif((float)ph * (2.0f / 1048576.0f), &s, &c);
    float vr = Br[lpad(k1)], vi = Bi[lpad(k1)];
    // multiply by e^{-2*pi*i*ph/2^20} = c - i s
    ws0[(size_t)b * 1024 + k1] = make_float2(vr * c + vi * s, vi * c - vr * s);
  }
}

__global__ __launch_bounds__(256) void k_fwd_passB(const float2* __restrict__ ws0,
                                                   float2* __restrict__ fhat)
{
  __shared__ float Ar[PADN], Ai[PADN], Br[PADN], Bi[PADN];
  const int b = swz(blockIdx.x);   // k1
  const int tid = threadIdx.x;
#pragma unroll
  for (int q = 0; q < 4; ++q) {
    int j = tid + 256 * q;         // n2
    float2 v = ws0[(size_t)j * 1024 + b];
    Ar[lpad(j)] = v.x; Ai[lpad(j)] = v.y;
  }
  __syncthreads();
  fft1024<-1>(Ar, Ai, Br, Bi);
#pragma unroll
  for (int q = 0; q < 4; ++q) {
    int k2 = tid + 256 * q;
    fhat[(size_t)b * 1024 + k2] = make_float2(Br[lpad(k2)], Bi[lpad(k2)]);
  }
}

// ---------------- iteration helpers ----------------
static __device__ __forceinline__ bool conv_at(const double* __restrict__ acc, int m)
{
  // acc slot j at acc[j*64 + m]; zeros (inactive iteration) => false
  double a6 = acc[6 * 64 + m], a7 = acc[7 * 64 + m];
  if (!(a6 < 1e-6 * a7)) return false;
  float o0 = (float)(acc[0 * 64 + m] / acc[3 * 64 + m]);
  float o1 = (float)(acc[1 * 64 + m] / acc[4 * 64 + m]);
  float o2 = (float)(acc[2 * 64 + m] / acc[5 * 64 + m]);
  float omd = (fabsf(o0 - o2) + fabsf(o1 - o0) + fabsf(o2 - o1)) * (1.0f / 3.0f);
  return omd < 1e-6f;
}

// ---------------- one VMD fixed-point iteration ----------------
__global__ __launch_bounds__(256) void k_vmd_iter(
    const float2* __restrict__ fhat, float2* __restrict__ lam,
    float2* __restrict__ lam_old, const float* __restrict__ omega0,
    double* __restrict__ acc, int n)
{
  __shared__ float sb[8];
  __shared__ double red[4][8];
  const int tid = threadIdx.x;
  const bool check = (n > 0) && (n % 10 == 0);
  const bool wold  = ((n % 10) == 9) || check;
  const bool first = (n == 0);

  if (tid == 0) {
    bool done = false;
    for (int m = 10; m < n; m += 10) if (conv_at(acc, m)) { done = true; break; }
    if (first) { sb[0] = omega0[0]; sb[1] = omega0[1]; sb[2] = omega0[2]; }
    else {
      sb[0] = (float)(acc[0 * 64 + n - 1] / acc[3 * 64 + n - 1]);
      sb[1] = (float)(acc[1 * 64 + n - 1] / acc[4 * 64 + n - 1]);
      sb[2] = (float)(acc[2 * 64 + n - 1] / acc[5 * 64 + n - 1]);
    }
    if (check) {
      sb[3] = (float)(acc[0 * 64 + n - 2] / acc[3 * 64 + n - 2]);
      sb[4] = (float)(acc[1 * 64 + n - 2] / acc[4 * 64 + n - 2]);
      sb[5] = (float)(acc[2 * 64 + n - 2] / acc[5 * 64 + n - 2]);
    } else { sb[3] = 0.f; sb[4] = 0.f; sb[5] = 0.f; }
    sb[6] = done ? 1.0f : 0.0f;
  }
  __syncthreads();
  if (sb[6] != 0.0f) return;   // frozen: nothing to do
  const float om0 = sb[0], om1 = sb[1], om2 = sb[2];
  const float pm0 = sb[3], pm1 = sb[4], pm2 = sb[5];

  const float TAU2 = TAU_F * TAU_F;
  double p0 = 0, p1 = 0, p2 = 0, p3 = 0, p4 = 0, p5 = 0, p6 = 0, p7 = 0;
  const int gid = blockIdx.x * 256 + tid;

#pragma unroll
  for (int h2 = 0; h2 < 2; ++h2) {
    const int f4i = gid * 2 + h2;                 // covers elements 4*gid+2*h2 .. +1
    const float4 fv = ((const float4*)fhat)[f4i];
    float4 lv;
    if (first) lv = make_float4(0.f, 0.f, 0.f, 0.f);
    else       lv = ((const float4*)lam)[f4i];
    float4 lov = make_float4(0.f, 0.f, 0.f, 0.f);
    if (check)  lov = ((const float4*)lam_old)[f4i];
    float4 nl;
#pragma unroll
    for (int c = 0; c < 2; ++c) {
      const int s = f4i * 2 + c;
      const float fr = c ? fv.z : fv.x, fi = c ? fv.w : fv.y;
      const float lr = c ? lv.z : lv.x, li = c ? lv.w : lv.y;
      const int k2s = s & 1023, k1s = s >> 10;
      const int tt = ((k2s ^ 512) << 10) | k1s;
      const float freq = (float)tt * (1.0f / 1048576.0f) - 0.5f;
      float a0 = freq - om0, a1 = freq - om1, a2 = freq - om2;
      float d0 = a0 * a0, d1 = a1 * a1, d2 = a2 * a2;
      float w0 = 1.0f / (1.0f + ALPHA_F * (d0 + d1 + TAU2));
      float w1 = 1.0f / (1.0f + ALPHA_F * (d0 + d1 + d2 + TAU2));
      float w2 = 1.0f / (1.0f + ALPHA_F * (d1 + d2 + TAU2));
      float hr = fr - 0.5f * lr, hi = fi - 0.5f * li;
      float g = hr * hr + hi * hi;
      float gw0 = g * w0 * w0, gw1 = g * w1 * w1, gw2 = g * w2 * w2;
      p0 += (double)(freq * gw0); p1 += (double)(freq * gw1); p2 += (double)(freq * gw2);
      p3 += (double)gw0;          p4 += (double)gw1;          p5 += (double)gw2;
      float S = w0 + w1 + w2;
      float nlr = lr + TAU_F * (hr * S - fr);
      float nli = li + TAU_F * (hi * S - fi);
      if (c == 0) { nl.x = nlr; nl.y = nli; } else { nl.z = nlr; nl.w = nli; }
      if (check) {
        const float plr = c ? lov.z : lov.x, pli = c ? lov.w : lov.y;
        float hpr = fr - 0.5f * plr, hpi = fi - 0.5f * pli;
        float b0 = freq - pm0, b1 = freq - pm1, b2 = freq - pm2;
        float e0 = b0 * b0, e1 = b1 * b1, e2 = b2 * b2;
        float v0 = 1.0f / (1.0f + ALPHA_F * (e0 + e1 + TAU2));
        float v1 = 1.0f / (1.0f + ALPHA_F * (e0 + e1 + e2 + TAU2));
        float v2 = 1.0f / (1.0f + ALPHA_F * (e1 + e2 + TAU2));
        float dr, di;
        dr = hr * w0 - hpr * v0; di = hi * w0 - hpi * v0; p6 += (double)(dr * dr + di * di);
        dr = hr * w1 - hpr * v1; di = hi * w1 - hpi * v1; p6 += (double)(dr * dr + di * di);
        dr = hr * w2 - hpr * v2; di = hi * w2 - hpi * v2; p6 += (double)(dr * dr + di * di);
        float gp = hpr * hpr + hpi * hpi;
        p7 += (double)(gp * (v0 * v0 + v1 * v1 + v2 * v2));
      }
    }
    ((float4*)lam)[f4i] = nl;
    if (wold) ((float4*)lam_old)[f4i] = lv;   // snapshot of lam at iteration entry
  }

  // reduce 8 double partials: wave shuffle -> LDS -> 8 atomics/block
  double pv[8] = { p0, p1, p2, p3, p4, p5, p6, p7 };
  const int lane = tid & 63, wv = tid >> 6;
#pragma unroll
  for (int j = 0; j < 8; ++j) {
    double v = pv[j];
    for (int off = 32; off; off >>= 1) v += __shfl_down(v, off, 64);
    if (lane == 0) red[wv][j] = v;
  }
  __syncthreads();
  if (tid < 8) {
    double ssum = red[0][tid] + red[1][tid] + red[2][tid] + red[3][tid];
    unsafeAtomicAdd(&acc[tid * 64 + n], ssum);  // native f64 atomic, slots on distinct lines
  }
}

// ---------------- inverse FFT (per mode) ----------------
__global__ __launch_bounds__(256) void k_inv_passA(
    const float2* __restrict__ fhat, const float2* __restrict__ lam_old,
    const double* __restrict__ acc, float2* __restrict__ ws0, int mode)
{
  __shared__ float Ar[PADN], Ai[PADN], Br[PADN], Bi[PADN];
  __shared__ float som[3];
  const int tid = threadIdx.x;
  if (tid == 0) {
    int nstar = 49;
    for (int m = 10; m <= 40; m += 10) if (conv_at(acc, m)) { nstar = m; break; }
    som[0] = (float)(acc[0 * 64 + nstar - 1] / acc[3 * 64 + nstar - 1]);
    som[1] = (float)(acc[1 * 64 + nstar - 1] / acc[4 * 64 + nstar - 1]);
    som[2] = (float)(acc[2 * 64 + nstar - 1] / acc[5 * 64 + nstar - 1]);
  }
  __syncthreads();
  const float om0 = som[0], om1 = som[1], om2 = som[2];
  const int b = swz(blockIdx.x);   // n2
  const float TAU2 = TAU_F * TAU_F;
#pragma unroll
  for (int q = 0; q < 4; ++q) {
    int j = tid + 256 * q;         // n1 ; ifftshift cancels: contiguous load
    float2 f  = fhat[(size_t)b * 1024 + j];
    float2 lo = lam_old[(size_t)b * 1024 + j];
    float hr = f.x - 0.5f * lo.x, hi = f.y - 0.5f * lo.y;
    int tt = ((j ^ 512) << 10) | b;
    float freq = (float)tt * (1.0f / 1048576.0f) - 0.5f;
    float a0 = freq - om0, a1 = freq - om1, a2 = freq - om2;
    float d0 = a0 * a0, d1 = a1 * a1, d2 = a2 * a2;
    float den = (mode == 0) ? (d0 + d1) : (mode == 1) ? (d0 + d1 + d2) : (d1 + d2);
    float wk = 1.0f / (1.0f + ALPHA_F * (den + TAU2));
    Ar[lpad(j)] = hr * wk; Ai[lpad(j)] = hi * wk;
  }
  __syncthreads();
  fft1024<1>(Ar, Ai, Br, Bi);
#pragma unroll
  for (int q = 0; q < 4; ++q) {
    int m1 = tid + 256 * q;
    int ph = b * m1;
    float s, c;
    sincospif((float)ph * (2.0f / 1048576.0f), &s, &c);
    float vr = Br[lpad(m1)], vi = Bi[lpad(m1)];
    // multiply by e^{+2*pi*i*ph/2^20} = c + i s
    ws0[(size_t)b * 1024 + m1] = make_float2(vr * c - vi * s, vi * c + vr * s);
  }
}

__global__ __launch_bounds__(256) void k_inv_passB(const float2* __restrict__ ws0,
                                                   float* __restrict__ out)
{
  __shared__ float Ar[PADN], Ai[PADN], Br[PADN], Bi[PADN];
  const int b = swz(blockIdx.x);   // m1
  const int tid = threadIdx.x;
#pragma unroll
  for (int q = 0; q < 4; ++q) {
    int j = tid + 256 * q;         // n2
    float2 v = ws0[(size_t)j * 1024 + b];
    Ar[lpad(j)] = v.x; Ai[lpad(j)] = v.y;
  }
  __syncthreads();
  fft1024<1>(Ar, Ai, Br, Bi);
#pragma unroll
  for (int q = 0; q < 4; ++q) {
    int m2 = tid + 256 * q;
    out[(size_t)m2 * 1024 + b] = Br[lpad(m2)] * (1.0f / 1048576.0f);
  }
}

// ---------------- host launch ----------------
extern "C" void kernel_launch(void* const* d_in, const int* in_sizes, int n_in,
                              void* d_out, int out_size, void* d_ws, size_t ws_size,
                              hipStream_t stream)
{
  (void)in_sizes; (void)n_in; (void)out_size; (void)ws_size;
  const float* x       = (const float*)d_in[0];
  const float* om_init = (const float*)d_in[1];
  float* out = (float*)d_out;

  char* w = (char*)d_ws;
  const size_t MB = 1024ull * 1024ull;
  float2* fhat    = (float2*)(w);
  float2* lam     = (float2*)(w + 8 * MB);
  float2* lam_old = (float2*)(w + 16 * MB);
  float2* scratch = (float2*)(w + 24 * MB);
  double* acc     = (double*)(w + 32 * MB);
  float*  omega0  = (float*)(w + 32 * MB + 8192);

  k_init<<<1, 256, 0, stream>>>(acc, omega0, om_init);
  k_fwd_passA<<<1024, 256, 0, stream>>>(x, scratch);
  k_fwd_passB<<<1024, 256, 0, stream>>>(scratch, fhat);
  for (int n = 0; n < 50; ++n)
    k_vmd_iter<<<1024, 256, 0, stream>>>(fhat, lam, lam_old, omega0, acc, n);
  for (int mode = 0; mode < 3; ++mode) {
    k_inv_passA<<<1024, 256, 0, stream>>>(fhat, lam_old, acc, scratch, mode);
    k_inv_passB<<<1024, 256, 0, stream>>>(scratch, out + (size_t)mode * 1048576ull);
  }
}